// Round 1
// 762.025 us; speedup vs baseline: 1.0066x; 1.0066x over previous
//
#include <hip/hip_runtime.h>
#include <hip/hip_bf16.h>
#include <cstdint>

#define B_   256
#define L_   196
#define ENC_ 2048
#define DEC_ 512
#define ATT_ 512
#define M_TOT (B_*L_)   // 50176, divisible by 64

typedef short short8 __attribute__((ext_vector_type(8)));
typedef float f32x16 __attribute__((ext_vector_type(16)));

__device__ __forceinline__ unsigned short f2bf(float f) {
    union { float f; unsigned u; } v; v.f = f;
    unsigned u = v.u;
    return (unsigned short)((u + 0x7FFFu + ((u >> 16) & 1u)) >> 16);  // RNE
}

__device__ __forceinline__ void gl_lds16(const void* g, void* l) {
    __builtin_amdgcn_global_load_lds((const __attribute__((address_space(1))) unsigned int*)g,
                                     (__attribute__((address_space(3))) unsigned int*)l,
                                     16, 0, 0);
}

// ---------- K0a: W_enc [ENC][ATT] fp32 -> WT [ATT][ENC] bf16 (transpose+convert) ----------
__global__ void k_transpose(const float* __restrict__ W, unsigned short* __restrict__ WT) {
    __shared__ float S[32*33];
    const int k0 = blockIdx.x * 32, n0 = blockIdx.y * 32;
    const int t  = threadIdx.x;
    const int c31 = t & 31, q = t >> 5;   // q = 0..7
#pragma unroll
    for (int i = 0; i < 4; ++i) {
        int kl = q + i*8;
        S[c31*33 + kl] = W[(size_t)(k0+kl)*ATT_ + n0 + c31];   // coalesced along n
    }
    __syncthreads();
#pragma unroll
    for (int i = 0; i < 4; ++i) {
        int nn = q + i*8;
        WT[(size_t)(n0+nn)*ENC_ + k0 + c31] = f2bf(S[nn*33 + c31]);  // coalesced along k
    }
}

// ---------- K0b: att2c[b][n] = h[b]@W_dec + b_dec + b_enc ; gate[b] = sigmoid(h@W_beta+b_beta) ----------
__global__ void k_prep2(const float* __restrict__ h, const float* __restrict__ Wdec,
                        const float* __restrict__ bdec, const float* __restrict__ benc,
                        const float* __restrict__ Wbeta, const float* __restrict__ bbeta,
                        float* __restrict__ att2c, float* __restrict__ gate) {
    const int b = blockIdx.x, t = threadIdx.x;   // 256 threads
    __shared__ float hs[DEC_];
    __shared__ float pr[4];
    hs[t]       = h[(size_t)b*DEC_ + t];
    hs[t + 256] = h[(size_t)b*DEC_ + t + 256];
    __syncthreads();
    float a0 = 0.f, a1 = 0.f;
    for (int k = 0; k < DEC_; ++k) {
        float hk = hs[k];
        a0 = fmaf(hk, Wdec[(size_t)k*ATT_ + t],       a0);
        a1 = fmaf(hk, Wdec[(size_t)k*ATT_ + t + 256], a1);
    }
    att2c[(size_t)b*ATT_ + t]       = a0 + bdec[t]       + benc[t];
    att2c[(size_t)b*ATT_ + t + 256] = a1 + bdec[t + 256] + benc[t + 256];
    float p = hs[t]*Wbeta[t] + hs[t+256]*Wbeta[t+256];
#pragma unroll
    for (int mask = 32; mask; mask >>= 1) p += __shfl_xor(p, mask, 64);
    if ((t & 63) == 0) pr[t >> 6] = p;
    __syncthreads();
    if (t == 0) gate[b] = 1.f / (1.f + __expf(-(pr[0]+pr[1]+pr[2]+pr[3] + bbeta[0])));
}

// ---------- K1: att[m] = sum_n relu(x[m]@W_enc[:,n] + att2c[b(m)][n]) * W_full[n] ----------
// 256 threads = 4 waves. Block tile 64(M) x 512(N), BK=32, double-buffered LDS.
// NEW schedule (T4, counted-vmcnt + raw s_barrier):
//   - B staging is WAVE-PRIVATE (each wave gl_lds's and reads only its own 128-row n-strip)
//     -> B needs no barrier, only within-wave vmcnt ordering.
//   - Only the cooperatively-staged A tile needs the barrier; barrier carries COUNTED
//     s_waitcnt vmcnt(10) (leaves next x-loads [2] + next B gl_lds [8] in flight) instead of
//     __syncthreads' vmcnt(0) full drain.
//   - x (fp32 A source, HBM ~900cy) prefetched TWO iterations ahead into a ping-pong register
//     pair (statically indexed via 2x-unrolled loop; rule #20).
// Steady-state invariant entering iter K (cur = K&1):
//   LDS[cur] holds A(K),B(K); outstanding vmem, oldest->newest:
//   [x(K+1):2, B(K+1):8]  (issued iter K-1).
// Iter K: issue x(K+2)[2]; ds_read 12 frags from cur; lgkmcnt(0); issue B(K+2)->Bb[cur][8];
//   16 MFMA; cvt x(K+1) (compiler emits precise counted vmcnt for it) -> ds_write A(K+1)->Ab[nxt];
//   asm { s_waitcnt vmcnt(10) lgkmcnt(0); s_barrier }.  vmcnt(10) drains B(K+1)+x(K+1) exactly,
//   keeping x(K+2)+B(K+2) (=10) in flight across the barrier.
__global__ __launch_bounds__(256, 2) void k_gemm(
        const float* __restrict__ x, const unsigned short* __restrict__ WT,
        const float* __restrict__ att2c, const float* __restrict__ Wfull,
        float* __restrict__ att) {
    __shared__ alignas(16) unsigned short Ab[2][64*32];    // 4 KB each
    __shared__ alignas(16) unsigned short Bb[2][512*32];   // 32 KB each
    __shared__ float att_ws[4][64];

    const int tid   = threadIdx.x;
    const int wave  = tid >> 6;
    const int lane  = tid & 63;
    const int lane31 = lane & 31;
    const int laneh  = lane >> 5;
    const int m0 = blockIdx.x * 64;

    f32x16 acc[2][4];
#pragma unroll
    for (int i = 0; i < 2; ++i)
#pragma unroll
        for (int j = 0; j < 4; ++j)
#pragma unroll
            for (int r = 0; r < 16; ++r) acc[i][j][r] = 0.f;

    // B staging: 8 gl_lds (1KB each) per wave per iter; per-lane source offset precomputed.
    int boff[8];
#pragma unroll
    for (int j = 0; j < 8; ++j) {
        int c  = (wave*8 + j)*64 + lane;
        int n  = c >> 2;
        int kc = (c & 3) ^ ((n >> 1) & 3);
        boff[j] = n*ENC_ + kc*8;
    }
    // A staging: thread -> (row ar, 8-float k-group g); one b128 ds_write per thread per iter.
    const int ar = tid >> 2, g = tid & 3;
    const int achunk = ar*4 + (g ^ ((ar >> 1) & 3));
    const float* xrow = x + (size_t)(m0 + ar)*ENC_ + g*8;

    // ---- prologue: stage B(0),B(1) via gl_lds; x(0),x(1) to regs; A(0) to LDS[0] ----
    float4 pa0, pb0, pa1, pb1;
#pragma unroll
    for (int j = 0; j < 8; ++j)
        gl_lds16(WT + boff[j], (void*)&Bb[0][(wave*8 + j)*512]);
    pa0 = *(const float4*)(xrow);
    pb0 = *(const float4*)(xrow + 4);
#pragma unroll
    for (int j = 0; j < 8; ++j)
        gl_lds16(WT + boff[j] + 32, (void*)&Bb[1][(wave*8 + j)*512]);
    pa1 = *(const float4*)(xrow + 32);
    pb1 = *(const float4*)(xrow + 36);
    {
        short8 w;
        w[0] = f2bf(pa0.x); w[1] = f2bf(pa0.y); w[2] = f2bf(pa0.z); w[3] = f2bf(pa0.w);
        w[4] = f2bf(pb0.x); w[5] = f2bf(pb0.y); w[6] = f2bf(pb0.z); w[7] = f2bf(pb0.w);
        *(short8*)&Ab[0][achunk*8] = w;
    }
    // Drain B(0)+x(0) (oldest 10); keep B(1)+x(1) (newest 10) in flight; publish A(0).
    asm volatile("s_waitcnt vmcnt(10) lgkmcnt(0)\n\ts_barrier" ::: "memory");

#define GEMM_ITER(K, XW0, XW1, XR0, XR1)                                              \
{                                                                                     \
    const int cur = (K) & 1, nxt = cur ^ 1;                                           \
    if ((K) + 2 < 64) {  /* issue x(K+2) two iters ahead */                           \
        XW0 = *(const float4*)(xrow + ((K)+2)*32);                                    \
        XW1 = *(const float4*)(xrow + ((K)+2)*32 + 4);                                \
    }                                                                                 \
    short8 a[2][2], bf[2][4];                                                         \
    _Pragma("unroll") for (int ks = 0; ks < 2; ++ks) {                                \
        _Pragma("unroll") for (int mi = 0; mi < 2; ++mi) {                            \
            int m  = mi*32 + lane31;                                                  \
            int ch = m*4 + ((ks*2 + laneh) ^ ((m >> 1) & 3));                         \
            a[ks][mi] = *(const short8*)&Ab[cur][ch*8];                               \
        }                                                                             \
        _Pragma("unroll") for (int ni = 0; ni < 4; ++ni) {                            \
            int n  = wave*128 + ni*32 + lane31;                                       \
            int ch = n*4 + ((ks*2 + laneh) ^ ((n >> 1) & 3));                         \
            bf[ks][ni] = *(const short8*)&Bb[cur][ch*8];                              \
        }                                                                             \
    }                                                                                 \
    /* all reads of Bb[cur] retired -> safe to re-target its region with DMA */       \
    asm volatile("s_waitcnt lgkmcnt(0)" ::: "memory");                                \
    if ((K) + 2 < 64) {                                                               \
        _Pragma("unroll") for (int j = 0; j < 8; ++j)                                 \
            gl_lds16(WT + boff[j] + ((K)+2)*32, (void*)&Bb[cur][(wave*8 + j)*512]);   \
    }                                                                                 \
    _Pragma("unroll") for (int ks = 0; ks < 2; ++ks)                                  \
        _Pragma("unroll") for (int mi = 0; mi < 2; ++mi)                              \
            _Pragma("unroll") for (int ni = 0; ni < 4; ++ni)                          \
                acc[mi][ni] = __builtin_amdgcn_mfma_f32_32x32x16_bf16(                \
                                  a[ks][mi], bf[ks][ni], acc[mi][ni], 0, 0, 0);       \
    if ((K) + 1 < 64) {  /* A(K+1) from x(K+1): arrived ~1.5 iters ago */             \
        short8 w;                                                                     \
        w[0] = f2bf(XR0.x); w[1] = f2bf(XR0.y); w[2] = f2bf(XR0.z); w[3] = f2bf(XR0.w);\
        w[4] = f2bf(XR1.x); w[5] = f2bf(XR1.y); w[6] = f2bf(XR1.z); w[7] = f2bf(XR1.w);\
        *(short8*)&Ab[nxt][achunk*8] = w;                                             \
    }                                                                                 \
    if ((K) < 62)                                                                     \
        asm volatile("s_waitcnt vmcnt(10) lgkmcnt(0)\n\ts_barrier" ::: "memory");     \
    else                                                                              \
        asm volatile("s_waitcnt vmcnt(0) lgkmcnt(0)\n\ts_barrier" ::: "memory");      \
}

    for (int K = 0; K < 64; K += 2) {
        GEMM_ITER(K,     pa0, pb0, pa1, pb1)   // even: x(K+2)->pa0/pb0, A from pa1/pb1
        GEMM_ITER(K + 1, pa1, pb1, pa0, pb0)   // odd : swapped ping-pong
    }
#undef GEMM_ITER

    // ---- epilogue: relu(acc + att2c[b][n]) * Wfull[n], reduce over n, write att[m] ----
    // All waves passed iter-63's barrier; Bb[0]'s last read was iter 62 -> safe to reuse.
    float* epi = (float*)&Bb[0][0];  // [0..511]=Wfull, [512..1023]=att2c[b0], [1024..1535]=att2c[b1]
    {
        const int b0i = m0 / L_;
        const int b1i = (m0 + 63) / L_;
        epi[tid]        = Wfull[tid];
        epi[256 + tid]  = Wfull[256 + tid];
        epi[512 + tid]  = att2c[(size_t)b0i*ATT_ + tid];
        epi[768 + tid]  = att2c[(size_t)b0i*ATT_ + 256 + tid];
        epi[1024 + tid] = att2c[(size_t)b1i*ATT_ + tid];
        epi[1280 + tid] = att2c[(size_t)b1i*ATT_ + 256 + tid];
    }
    __syncthreads();
    const int split = (m0 / L_ + 1) * L_;   // first global row of batch b1
#pragma unroll
    for (int mi = 0; mi < 2; ++mi) {
#pragma unroll
        for (int reg = 0; reg < 16; ++reg) {
            int r32  = (reg & 3) + 8*(reg >> 2) + 4*laneh;   // verified C/D map (m74/m101)
            int mloc = mi*32 + r32;
            int off  = (m0 + mloc >= split) ? 1024 : 512;
            float v = 0.f;
#pragma unroll
            for (int ni = 0; ni < 4; ++ni) {
                int n = wave*128 + ni*32 + lane31;
                float tv = acc[mi][ni][reg] + epi[off + n];
                v = fmaf(fmaxf(tv, 0.f), epi[n], v);
            }
#pragma unroll
            for (int mask = 16; mask; mask >>= 1) v += __shfl_xor(v, mask, 64);
            if (lane31 == 0) att_ws[wave][mloc] = v;
        }
    }
    __syncthreads();
    if (tid < 64)
        att[m0 + tid] = att_ws[0][tid] + att_ws[1][tid] + att_ws[2][tid] + att_ws[3][tid];
}

// ---------- K2: softmax over L, z = alpha@x[b], out0 = gate*z, out1 = alpha ----------
// grid (B, 2): each block handles 1024 of 2048 ENC cols -> 512 blocks = 2/CU.
// Block order REVERSED (b = 255-blockIdx.x): k_gemm streams x ascending, so L3 holds the
// tail of x when this launches -> reversed order starts in L3-resident data, and finishes
// at the head of x, which the NEXT iteration's k_gemm (ascending) then hits in L3.
// z-loop: explicit one-group-ahead software pipeline (7+7 float4 in flight) so the
// accumulation can't serialize on HBM latency at only 8 waves/CU.
__global__ __launch_bounds__(256) void k_softz(
        const float* __restrict__ att, const float* __restrict__ x,
        const float* __restrict__ gate, float* __restrict__ out) {
    const int b = (B_ - 1) - (int)blockIdx.x;
    const int s = blockIdx.y, t = threadIdx.x;   // 256 threads
    __shared__ float sa[L_];
    __shared__ float red[8];
    const int wid = t >> 6, lane = t & 63;
    float v = (t < L_) ? att[b*L_ + t] : -1e30f;
    float m = v;
#pragma unroll
    for (int mask = 32; mask; mask >>= 1) m = fmaxf(m, __shfl_xor(m, mask, 64));
    if (lane == 0) red[wid] = m;
    __syncthreads();
    m = fmaxf(fmaxf(red[0], red[1]), fmaxf(red[2], red[3]));
    float e = (t < L_) ? __expf(v - m) : 0.f;
    float sum = e;
#pragma unroll
    for (int mask = 32; mask; mask >>= 1) sum += __shfl_xor(sum, mask, 64);
    if (lane == 0) red[4 + wid] = sum;
    __syncthreads();
    sum = red[4] + red[5] + red[6] + red[7];
    float alpha = e / sum;
    if (t < L_) {
        sa[t] = alpha;
        if (s == 0) out[(size_t)B_*ENC_ + (size_t)b*L_ + t] = alpha;
    }
    __syncthreads();
    const float* xb = x + (size_t)b*L_*ENC_ + s*1024 + t*4;
    float4 z = {0.f, 0.f, 0.f, 0.f};
    float4 u[7], w[7];
#pragma unroll
    for (int i = 0; i < 7; ++i) u[i] = *(const float4*)(xb + (size_t)i*ENC_);
    for (int l0 = 0; l0 < 183; l0 += 7) {          // consumes groups 0..182, prefetches 7..189
#pragma unroll
        for (int i = 0; i < 7; ++i)
            w[i] = *(const float4*)(xb + (size_t)(l0 + 7 + i)*ENC_);
#pragma unroll
        for (int i = 0; i < 7; ++i) {
            float a_ = sa[l0 + i];
            z.x = fmaf(a_, u[i].x, z.x); z.y = fmaf(a_, u[i].y, z.y);
            z.z = fmaf(a_, u[i].z, z.z); z.w = fmaf(a_, u[i].w, z.w);
        }
#pragma unroll
        for (int i = 0; i < 7; ++i) u[i] = w[i];
    }
#pragma unroll
    for (int i = 0; i < 7; ++i) {                  // final group l = 189..195
        float a_ = sa[189 + i];
        z.x = fmaf(a_, u[i].x, z.x); z.y = fmaf(a_, u[i].y, z.y);
        z.z = fmaf(a_, u[i].z, z.z); z.w = fmaf(a_, u[i].w, z.w);
    }
    const float gt = gate[b];
    float4 o; o.x = gt*z.x; o.y = gt*z.y; o.z = gt*z.z; o.w = gt*z.w;
    *(float4*)(out + (size_t)b*ENC_ + s*1024 + t*4) = o;
}

extern "C" void kernel_launch(void* const* d_in, const int* in_sizes, int n_in,
                              void* d_out, int out_size, void* d_ws, size_t ws_size,
                              hipStream_t stream) {
    const float* x      = (const float*)d_in[0];
    const float* h      = (const float*)d_in[1];
    const float* W_enc  = (const float*)d_in[2];
    const float* b_enc  = (const float*)d_in[3];
    const float* W_dec  = (const float*)d_in[4];
    const float* b_dec  = (const float*)d_in[5];
    const float* W_full = (const float*)d_in[6];
    // d_in[7] = b_full: softmax is shift-invariant -> unused
    const float* W_beta = (const float*)d_in[8];
    const float* b_beta = (const float*)d_in[9];
    float* out = (float*)d_out;

    char* ws = (char*)d_ws;
    unsigned short* WT = (unsigned short*)ws;                              // 2 MB
    float* att2c  = (float*)(ws + 2*1024*1024);                            // 512 KB
    float* gate   = (float*)(ws + 2*1024*1024 + 512*1024);                 // 1 KB
    float* attbuf = (float*)(ws + 2*1024*1024 + 512*1024 + 1024);          // 200 KB

    k_transpose<<<dim3(ENC_/32, ATT_/32), 256, 0, stream>>>(W_enc, WT);
    k_prep2   <<<B_, 256, 0, stream>>>(h, W_dec, b_dec, b_enc, W_beta, b_beta, att2c, gate);
    k_gemm    <<<M_TOT/64, 256, 0, stream>>>(x, WT, att2c, W_full, attbuf);
    k_softz   <<<dim3(B_, 2), 256, 0, stream>>>(attbuf, x, gate, out);
}